// Round 3
// baseline (227.253 us; speedup 1.0000x reference)
//
#include <hip/hip_runtime.h>

// out[s,b,d] = x[s,b,d] + pe[s,d] + (any_p peaks[b,p]==s ? table[s,d] : 0)
// S=256, B=2048, D=256, P=8. Pure stream: 512MB read + 512MB write.
//
// R3: BTILE=256 -> grid=2048 blocks = 8 blocks/CU x 4 waves = exactly one
// fully-resident round (no second-round tail, half the prologues). Plain
// (non-NT) loads/stores to match the measured 6.29 TB/s copy config.
// Hot loop stays LDS-free: pe / pe+table in registers, mask in 4 u64 words.

typedef float f32x4 __attribute__((ext_vector_type(4)));

namespace {
constexpr int S       = 256;
constexpr int Bn      = 2048;
constexpr int P       = 8;
constexpr int D4      = 64;            // 256 floats / 4
constexpr int BTILE   = 256;           // batches per block
constexpr int NBT     = Bn / BTILE;    // 8
constexpr int THREADS = 256;
constexpr int ITERS   = BTILE * D4 / THREADS;  // 64 float4 per thread
constexpr int CHUNK   = 8;
}

__global__ __launch_bounds__(THREADS, 8)
void pe_peak_kernel(const float* __restrict__ x,
                    const unsigned* __restrict__ pk,   // int32 or int64 data
                    const float* __restrict__ table,
                    float* __restrict__ out)
{
    __shared__ f32x4 s_pe[D4];              // pe[s, :]
    __shared__ f32x4 s_pt[D4];              // pe[s, :] + table[s, :]
    __shared__ unsigned long long s_mb[4];  // 256 per-batch peak-hit bits
    __shared__ int s_is64;

    const int t  = threadIdx.x;
    const int s  = blockIdx.x >> 3;               // / NBT
    const int b0 = (blockIdx.x & (NBT - 1)) * BTILE;

    // --- int64 vs int32 width detect: values < 300, so int64 => all high
    //     words zero; int32 => 32 consecutive zero words ~impossible. --------
    {
        unsigned hw = (t < 32) ? pk[2 * t + 1] : 0u;
        unsigned long long nz = __ballot(hw != 0u);
        if (t == 0) s_is64 = (nz == 0ull) ? 1 : 0;
    }

    // --- pe[s,:] on the fly + pe+table staged once (threads 0..63) ---------
    if (t < D4) {
        const float c = -6.907755278982137f / 256.0f;   // -ln(1000)/D
        float a0 = (float)s * expf((float)(4 * t) * c);       // pair k=2t
        float a1 = (float)s * expf((float)(4 * t + 2) * c);   // pair k=2t+1
        f32x4 pe4;
        pe4.x = sinf(a0); pe4.y = cosf(a0);
        pe4.z = sinf(a1); pe4.w = cosf(a1);
        f32x4 tb4 = reinterpret_cast<const f32x4*>(table)[s * D4 + t];
        s_pe[t] = pe4;
        s_pt[t] = pe4 + tb4;
    }
    __syncthreads();   // publishes s_is64, s_pe, s_pt

    // --- per-batch "peak at s" bit, balloted into 4x u64 -------------------
    {
        const int b = b0 + t;
        bool m = false;
        if (s_is64) {
            #pragma unroll
            for (int p = 0; p < P; ++p) m |= (pk[(size_t)(b * P + p) * 2] == (unsigned)s);
        } else {
            #pragma unroll
            for (int p = 0; p < P; ++p) m |= (pk[b * P + p] == (unsigned)s);
        }
        unsigned long long bal = __ballot(m);
        if ((t & 63) == 0) s_mb[t >> 6] = bal;
    }
    __syncthreads();

    // --- hoist everything the hot loop needs into registers ----------------
    const int lane = t & 63;     // d4 index (loop-invariant per thread)
    const int w    = t >> 6;     // batch-row offset within each 4-row slab
    const f32x4 pe4 = s_pe[lane];
    const f32x4 pt4 = s_pt[lane];
    const unsigned long long mbw[4] = { s_mb[0], s_mb[1], s_mb[2], s_mb[3] };

    // --- stream 256x256 floats, chunks of 8 loads -> 8 add+stores ----------
    const size_t base = ((size_t)s * Bn + b0) * D4;
    const f32x4* __restrict__ xr = reinterpret_cast<const f32x4*>(x) + base;
    f32x4* __restrict__ orow     = reinterpret_cast<f32x4*>(out) + base;

    #pragma unroll
    for (int j0 = 0; j0 < ITERS; j0 += CHUNK) {
        f32x4 v[CHUNK];
        #pragma unroll
        for (int u = 0; u < CHUNK; ++u)
            v[u] = xr[(size_t)(j0 + u) * THREADS + t];
        #pragma unroll
        for (int u = 0; u < CHUNK; ++u) {
            const int j = j0 + u;
            // j>>4 is a compile-time constant under full unroll (rule #20 ok)
            const unsigned long long mb = mbw[j >> 4];
            const bool hit = (mb >> ((4 * j + w) & 63)) & 1ull;
            const f32x4 a = hit ? pt4 : pe4;
            orow[(size_t)j * THREADS + t] = v[u] + a;
        }
    }
}

extern "C" void kernel_launch(void* const* d_in, const int* in_sizes, int n_in,
                              void* d_out, int out_size, void* d_ws, size_t ws_size,
                              hipStream_t stream) {
    const float*    x     = (const float*)d_in[0];
    const unsigned* pk    = (const unsigned*)d_in[1];
    const float*    table = (const float*)d_in[2];
    float*          out   = (float*)d_out;

    pe_peak_kernel<<<dim3(S * NBT), dim3(THREADS), 0, stream>>>(x, pk, table, out);
}

// Round 4
// 210.145 us; speedup vs baseline: 1.0814x; 1.0814x over previous
//
#include <hip/hip_runtime.h>

// out[s,b,d] = x[s,b,d] + pe[s,d] + (any_p peaks[b,p]==s ? table[s,d] : 0)
// S=256, B=2048, D=256, P=8. Pure stream: 512MB read + 512MB write.
//
// R4: two-kernel split. Pre-kernel (tiny) materializes per-s rows
//   ws_pe[s][64] (f32x4), ws_pt[s][64] (pe+table), ws_mask[s][32] (u64 bitmask
//   over 2048 batches) into d_ws. Main kernel = R2's exact NT stream loop but
//   with a 4-load prologue: no barriers, no LDS, no transcendentals.
// Fallback to the R2 single-kernel path if ws_size < 576 KB.

typedef float f32x4 __attribute__((ext_vector_type(4)));

namespace {
constexpr int S       = 256;
constexpr int Bn      = 2048;
constexpr int P       = 8;
constexpr int D4      = 64;            // 256 floats / 4
constexpr int BTILE   = 128;           // batches per block (main kernel)
constexpr int NBT     = Bn / BTILE;    // 16
constexpr int THREADS = 256;
constexpr int ITERS   = BTILE * D4 / THREADS;  // 32 float4 per thread
constexpr int CHUNK   = 8;

constexpr size_t WS_PE_OFF   = 0;                       // S*64 f32x4 = 256 KB
constexpr size_t WS_PT_OFF   = (size_t)S * D4;          // in f32x4 units
constexpr size_t WS_MASK_OFF = (size_t)2 * S * D4 * 16; // byte offset of masks
constexpr size_t WS_NEEDED   = WS_MASK_OFF + (size_t)S * (Bn / 64) * 8; // 576 KB
}

// ---------------- pre-kernel: one block per s ------------------------------
__global__ __launch_bounds__(THREADS)
void pe_prep_kernel(const unsigned* __restrict__ pk,
                    const float* __restrict__ table,
                    f32x4* __restrict__ ws_pe,          // [S][64], pt at +S*64
                    unsigned long long* __restrict__ ws_mask)  // [S][32]
{
    const int s = blockIdx.x;
    const int t = threadIdx.x;

    // int64 vs int32 detect (values < 300 => int64 high words all zero)
    __shared__ int s_is64;
    {
        unsigned hw = (t < 32) ? pk[2 * t + 1] : 0u;
        unsigned long long nz = __ballot(hw != 0u);
        if (t == 0) s_is64 = (nz == 0ull) ? 1 : 0;
    }
    __syncthreads();
    const bool is64 = (s_is64 != 0);

    if (t < D4) {
        const float c = -6.907755278982137f / 256.0f;   // -ln(1000)/D
        float a0 = (float)s * expf((float)(4 * t) * c);
        float a1 = (float)s * expf((float)(4 * t + 2) * c);
        f32x4 pe4;
        pe4.x = sinf(a0); pe4.y = cosf(a0);
        pe4.z = sinf(a1); pe4.w = cosf(a1);
        f32x4 tb4 = reinterpret_cast<const f32x4*>(table)[s * D4 + t];
        ws_pe[(size_t)s * D4 + t]              = pe4;
        ws_pe[WS_PT_OFF + (size_t)s * D4 + t]  = pe4 + tb4;
    }

    // mask bits for 2048 batches: iteration k covers batches k*256 + t
    const int w = t >> 6;
    #pragma unroll
    for (int k = 0; k < Bn / THREADS; ++k) {
        const int b = k * THREADS + t;
        bool m = false;
        if (is64) {
            #pragma unroll
            for (int p = 0; p < P; ++p) m |= (pk[(size_t)(b * P + p) * 2] == (unsigned)s);
        } else {
            #pragma unroll
            for (int p = 0; p < P; ++p) m |= (pk[b * P + p] == (unsigned)s);
        }
        unsigned long long bal = __ballot(m);
        if ((t & 63) == 0) ws_mask[(size_t)s * (Bn / 64) + k * 4 + w] = bal;
    }
}

// ---------------- main kernel: barrier-free NT stream ----------------------
__global__ __launch_bounds__(THREADS)
void pe_stream_kernel(const float* __restrict__ x,
                      const f32x4* __restrict__ ws_pe,
                      const unsigned long long* __restrict__ ws_mask,
                      float* __restrict__ out)
{
    const int t  = threadIdx.x;
    const int s  = blockIdx.x >> 4;               // / NBT
    const int b0 = (blockIdx.x & (NBT - 1)) * BTILE;

    const int lane = t & 63;     // d4 index (loop-invariant per thread)
    const int w    = t >> 6;     // batch-row offset within each 4-row slab

    const f32x4 pe4 = ws_pe[(size_t)s * D4 + lane];
    const f32x4 pt4 = ws_pe[WS_PT_OFF + (size_t)s * D4 + lane];
    const unsigned long long mb0 = ws_mask[(size_t)s * (Bn / 64) + (b0 >> 6)];
    const unsigned long long mb1 = ws_mask[(size_t)s * (Bn / 64) + (b0 >> 6) + 1];

    const size_t base = ((size_t)s * Bn + b0) * D4;
    const f32x4* __restrict__ xr = reinterpret_cast<const f32x4*>(x) + base;
    f32x4* __restrict__ orow     = reinterpret_cast<f32x4*>(out) + base;

    #pragma unroll
    for (int j0 = 0; j0 < ITERS; j0 += CHUNK) {
        f32x4 v[CHUNK];
        #pragma unroll
        for (int u = 0; u < CHUNK; ++u)
            v[u] = __builtin_nontemporal_load(xr + (size_t)(j0 + u) * THREADS + t);
        #pragma unroll
        for (int u = 0; u < CHUNK; ++u) {
            const int j = j0 + u;
            const unsigned long long mb = (j < 16) ? mb0 : mb1;  // compile-time
            const bool hit = (mb >> ((4 * j + w) & 63)) & 1ull;
            const f32x4 a = hit ? pt4 : pe4;
            __builtin_nontemporal_store(v[u] + a, orow + (size_t)j * THREADS + t);
        }
    }
}

// ---------------- fallback: R2 single-kernel (ws too small) ----------------
__global__ __launch_bounds__(THREADS)
void pe_peak_fused_kernel(const float* __restrict__ x,
                          const unsigned* __restrict__ pk,
                          const float* __restrict__ table,
                          float* __restrict__ out)
{
    __shared__ f32x4 s_pe[D4];
    __shared__ f32x4 s_pt[D4];
    __shared__ unsigned long long s_mb[2];
    __shared__ int s_is64;

    const int t  = threadIdx.x;
    const int s  = blockIdx.x >> 4;
    const int b0 = (blockIdx.x & (NBT - 1)) * BTILE;

    {
        unsigned hw = (t < 32) ? pk[2 * t + 1] : 0u;
        unsigned long long nz = __ballot(hw != 0u);
        if (t == 0) s_is64 = (nz == 0ull) ? 1 : 0;
    }

    if (t < D4) {
        const float c = -6.907755278982137f / 256.0f;
        float a0 = (float)s * expf((float)(4 * t) * c);
        float a1 = (float)s * expf((float)(4 * t + 2) * c);
        f32x4 pe4;
        pe4.x = sinf(a0); pe4.y = cosf(a0);
        pe4.z = sinf(a1); pe4.w = cosf(a1);
        f32x4 tb4 = reinterpret_cast<const f32x4*>(table)[s * D4 + t];
        s_pe[t] = pe4;
        s_pt[t] = pe4 + tb4;
    }
    __syncthreads();

    bool m = false;
    if (t < BTILE) {
        const int b = b0 + t;
        if (s_is64) {
            #pragma unroll
            for (int p = 0; p < P; ++p) m |= (pk[(size_t)(b * P + p) * 2] == (unsigned)s);
        } else {
            #pragma unroll
            for (int p = 0; p < P; ++p) m |= (pk[b * P + p] == (unsigned)s);
        }
    }
    {
        unsigned long long bal = __ballot(m);
        if (t < 128 && (t & 63) == 0) s_mb[t >> 6] = bal;
    }
    __syncthreads();

    const int lane = t & 63;
    const int w    = t >> 6;
    const f32x4 pe4 = s_pe[lane];
    const f32x4 pt4 = s_pt[lane];
    const unsigned long long mb0 = s_mb[0];
    const unsigned long long mb1 = s_mb[1];

    const size_t base = ((size_t)s * Bn + b0) * D4;
    const f32x4* __restrict__ xr = reinterpret_cast<const f32x4*>(x) + base;
    f32x4* __restrict__ orow     = reinterpret_cast<f32x4*>(out) + base;

    #pragma unroll
    for (int j0 = 0; j0 < ITERS; j0 += CHUNK) {
        f32x4 v[CHUNK];
        #pragma unroll
        for (int u = 0; u < CHUNK; ++u)
            v[u] = __builtin_nontemporal_load(xr + (size_t)(j0 + u) * THREADS + t);
        #pragma unroll
        for (int u = 0; u < CHUNK; ++u) {
            const int j = j0 + u;
            const unsigned long long mb = (j < 16) ? mb0 : mb1;
            const bool hit = (mb >> ((4 * j + w) & 63)) & 1ull;
            const f32x4 a = hit ? pt4 : pe4;
            __builtin_nontemporal_store(v[u] + a, orow + (size_t)j * THREADS + t);
        }
    }
}

extern "C" void kernel_launch(void* const* d_in, const int* in_sizes, int n_in,
                              void* d_out, int out_size, void* d_ws, size_t ws_size,
                              hipStream_t stream) {
    const float*    x     = (const float*)d_in[0];
    const unsigned* pk    = (const unsigned*)d_in[1];
    const float*    table = (const float*)d_in[2];
    float*          out   = (float*)d_out;

    if (ws_size >= WS_NEEDED) {
        f32x4* ws_pe = (f32x4*)d_ws;
        unsigned long long* ws_mask =
            (unsigned long long*)((char*)d_ws + WS_MASK_OFF);
        pe_prep_kernel<<<dim3(S), dim3(THREADS), 0, stream>>>(pk, table, ws_pe, ws_mask);
        pe_stream_kernel<<<dim3(S * NBT), dim3(THREADS), 0, stream>>>(x, ws_pe, ws_mask, out);
    } else {
        pe_peak_fused_kernel<<<dim3(S * NBT), dim3(THREADS), 0, stream>>>(x, pk, table, out);
    }
}

// Round 5
// 209.416 us; speedup vs baseline: 1.0852x; 1.0035x over previous
//
#include <hip/hip_runtime.h>

// out[s,b,d] = x[s,b,d] + pe[s,d] + (any_p peaks[b,p]==s ? table[s,d] : 0)
// S=256, B=2048, D=256, P=8. Pure stream: 512MB read + 512MB write.
//
// R5 = R2 with ONE change: plain (cached) stores instead of nontemporal
// stores. Rationale: fillBuffer (plain stores) sustains 6.7 TB/s on this
// chip; m13 copy ceiling (6.29 TB/s) is also plain-store. Loads stay NT
// (x is single-pass; no L2 pollution).

typedef float f32x4 __attribute__((ext_vector_type(4)));

namespace {
constexpr int S       = 256;
constexpr int Bn      = 2048;
constexpr int P       = 8;
constexpr int D4      = 64;            // 256 floats / 4
constexpr int BTILE   = 128;           // batches per block
constexpr int NBT     = Bn / BTILE;    // 16
constexpr int THREADS = 256;
constexpr int ITERS   = BTILE * D4 / THREADS;  // 32 float4 per thread
constexpr int CHUNK   = 8;
}

__global__ __launch_bounds__(THREADS)
void pe_peak_kernel(const float* __restrict__ x,
                    const unsigned* __restrict__ pk,   // int32 or int64 data
                    const float* __restrict__ table,
                    float* __restrict__ out)
{
    __shared__ f32x4 s_pe[D4];           // pe[s, :]
    __shared__ f32x4 s_pt[D4];           // pe[s, :] + table[s, :]
    __shared__ unsigned long long s_mb[2];  // 128 per-batch peak-hit bits
    __shared__ int s_is64;

    const int t  = threadIdx.x;
    const int s  = blockIdx.x >> 4;               // / NBT
    const int b0 = (blockIdx.x & (NBT - 1)) * BTILE;

    // --- int64 vs int32 width detect: values < 300, so int64 => all high
    //     words zero; int32 => 32 consecutive zero words ~impossible. --------
    {
        unsigned hw = (t < 32) ? pk[2 * t + 1] : 0u;
        unsigned long long nz = __ballot(hw != 0u);
        if (t == 0) s_is64 = (nz == 0ull) ? 1 : 0;
    }

    // --- pe[s,:] on the fly + pe+table staged once (threads 0..63) ---------
    if (t < D4) {
        const float c = -6.907755278982137f / 256.0f;   // -ln(1000)/D
        float a0 = (float)s * expf((float)(4 * t) * c);       // pair k=2t
        float a1 = (float)s * expf((float)(4 * t + 2) * c);   // pair k=2t+1
        f32x4 pe4;
        pe4.x = sinf(a0); pe4.y = cosf(a0);
        pe4.z = sinf(a1); pe4.w = cosf(a1);
        f32x4 tb4 = reinterpret_cast<const f32x4*>(table)[s * D4 + t];
        s_pe[t] = pe4;
        s_pt[t] = pe4 + tb4;
    }
    __syncthreads();

    // --- per-batch "peak at s" bit, balloted into 2x u64 -------------------
    bool m = false;
    if (t < BTILE) {
        const int b = b0 + t;
        if (s_is64) {
            #pragma unroll
            for (int p = 0; p < P; ++p) m |= (pk[(size_t)(b * P + p) * 2] == (unsigned)s);
        } else {
            #pragma unroll
            for (int p = 0; p < P; ++p) m |= (pk[b * P + p] == (unsigned)s);
        }
    }
    {
        unsigned long long bal = __ballot(m);
        if (t < 128 && (t & 63) == 0) s_mb[t >> 6] = bal;
    }
    __syncthreads();

    // --- hoist everything the hot loop needs into registers ----------------
    const int lane = t & 63;     // d4 index (loop-invariant)
    const int w    = t >> 6;     // batch-row offset within each 4-row slab
    const f32x4 pe4 = s_pe[lane];
    const f32x4 pt4 = s_pt[lane];
    const unsigned long long mb0 = s_mb[0];
    const unsigned long long mb1 = s_mb[1];

    // --- stream 128x256 floats, batched 8 NT loads -> 8 plain stores -------
    const size_t base = ((size_t)s * Bn + b0) * D4;
    const f32x4* __restrict__ xr = reinterpret_cast<const f32x4*>(x) + base;
    f32x4* __restrict__ orow     = reinterpret_cast<f32x4*>(out) + base;

    #pragma unroll
    for (int j0 = 0; j0 < ITERS; j0 += CHUNK) {
        f32x4 v[CHUNK];
        #pragma unroll
        for (int u = 0; u < CHUNK; ++u)
            v[u] = __builtin_nontemporal_load(xr + (size_t)(j0 + u) * THREADS + t);
        #pragma unroll
        for (int u = 0; u < CHUNK; ++u) {
            const int j = j0 + u;
            const unsigned long long mb = (j < 16) ? mb0 : mb1;   // compile-time select
            const bool hit = (mb >> ((4 * j + w) & 63)) & 1ull;
            const f32x4 a = hit ? pt4 : pe4;
            orow[(size_t)j * THREADS + t] = v[u] + a;             // plain store
        }
    }
}

extern "C" void kernel_launch(void* const* d_in, const int* in_sizes, int n_in,
                              void* d_out, int out_size, void* d_ws, size_t ws_size,
                              hipStream_t stream) {
    const float*    x     = (const float*)d_in[0];
    const unsigned* pk    = (const unsigned*)d_in[1];
    const float*    table = (const float*)d_in[2];
    float*          out   = (float*)d_out;

    pe_peak_kernel<<<dim3(S * NBT), dim3(THREADS), 0, stream>>>(x, pk, table, out);
}

// Round 6
// 208.909 us; speedup vs baseline: 1.0878x; 1.0024x over previous
//
#include <hip/hip_runtime.h>

// out[s,b,d] = x[s,b,d] + pe[s,d] + (any_p peaks[b,p]==s ? table[s,d] : 0)
// S=256, B=2048, D=256, P=8. Pure stream: 512MB read + 512MB write.
//
// R6 = R2 with ONE change: plain (cached) loads instead of nontemporal
// loads; stores stay NT (R2 vs R5 showed NT stores are +4%). Theory: L2
// read-combining is what the 6.29 TB/s copy ceiling uses; NT loads may
// bypass it. Completes the 2x2 load/store policy matrix.

typedef float f32x4 __attribute__((ext_vector_type(4)));

namespace {
constexpr int S       = 256;
constexpr int Bn      = 2048;
constexpr int P       = 8;
constexpr int D4      = 64;            // 256 floats / 4
constexpr int BTILE   = 128;           // batches per block
constexpr int NBT     = Bn / BTILE;    // 16
constexpr int THREADS = 256;
constexpr int ITERS   = BTILE * D4 / THREADS;  // 32 float4 per thread
constexpr int CHUNK   = 8;
}

__global__ __launch_bounds__(THREADS)
void pe_peak_kernel(const float* __restrict__ x,
                    const unsigned* __restrict__ pk,   // int32 or int64 data
                    const float* __restrict__ table,
                    float* __restrict__ out)
{
    __shared__ f32x4 s_pe[D4];           // pe[s, :]
    __shared__ f32x4 s_pt[D4];           // pe[s, :] + table[s, :]
    __shared__ unsigned long long s_mb[2];  // 128 per-batch peak-hit bits
    __shared__ int s_is64;

    const int t  = threadIdx.x;
    const int s  = blockIdx.x >> 4;               // / NBT
    const int b0 = (blockIdx.x & (NBT - 1)) * BTILE;

    // --- int64 vs int32 width detect: values < 300, so int64 => all high
    //     words zero; int32 => 32 consecutive zero words ~impossible. --------
    {
        unsigned hw = (t < 32) ? pk[2 * t + 1] : 0u;
        unsigned long long nz = __ballot(hw != 0u);
        if (t == 0) s_is64 = (nz == 0ull) ? 1 : 0;
    }

    // --- pe[s,:] on the fly + pe+table staged once (threads 0..63) ---------
    if (t < D4) {
        const float c = -6.907755278982137f / 256.0f;   // -ln(1000)/D
        float a0 = (float)s * expf((float)(4 * t) * c);       // pair k=2t
        float a1 = (float)s * expf((float)(4 * t + 2) * c);   // pair k=2t+1
        f32x4 pe4;
        pe4.x = sinf(a0); pe4.y = cosf(a0);
        pe4.z = sinf(a1); pe4.w = cosf(a1);
        f32x4 tb4 = reinterpret_cast<const f32x4*>(table)[s * D4 + t];
        s_pe[t] = pe4;
        s_pt[t] = pe4 + tb4;
    }
    __syncthreads();

    // --- per-batch "peak at s" bit, balloted into 2x u64 -------------------
    bool m = false;
    if (t < BTILE) {
        const int b = b0 + t;
        if (s_is64) {
            #pragma unroll
            for (int p = 0; p < P; ++p) m |= (pk[(size_t)(b * P + p) * 2] == (unsigned)s);
        } else {
            #pragma unroll
            for (int p = 0; p < P; ++p) m |= (pk[b * P + p] == (unsigned)s);
        }
    }
    {
        unsigned long long bal = __ballot(m);
        if (t < 128 && (t & 63) == 0) s_mb[t >> 6] = bal;
    }
    __syncthreads();

    // --- hoist everything the hot loop needs into registers ----------------
    const int lane = t & 63;     // d4 index (loop-invariant)
    const int w    = t >> 6;     // batch-row offset within each 4-row slab
    const f32x4 pe4 = s_pe[lane];
    const f32x4 pt4 = s_pt[lane];
    const unsigned long long mb0 = s_mb[0];
    const unsigned long long mb1 = s_mb[1];

    // --- stream 128x256 floats: 8 plain loads -> 8 add + NT stores ---------
    const size_t base = ((size_t)s * Bn + b0) * D4;
    const f32x4* __restrict__ xr = reinterpret_cast<const f32x4*>(x) + base;
    f32x4* __restrict__ orow     = reinterpret_cast<f32x4*>(out) + base;

    #pragma unroll
    for (int j0 = 0; j0 < ITERS; j0 += CHUNK) {
        f32x4 v[CHUNK];
        #pragma unroll
        for (int u = 0; u < CHUNK; ++u)
            v[u] = xr[(size_t)(j0 + u) * THREADS + t];            // plain load
        #pragma unroll
        for (int u = 0; u < CHUNK; ++u) {
            const int j = j0 + u;
            const unsigned long long mb = (j < 16) ? mb0 : mb1;   // compile-time select
            const bool hit = (mb >> ((4 * j + w) & 63)) & 1ull;
            const f32x4 a = hit ? pt4 : pe4;
            __builtin_nontemporal_store(v[u] + a, orow + (size_t)j * THREADS + t);
        }
    }
}

extern "C" void kernel_launch(void* const* d_in, const int* in_sizes, int n_in,
                              void* d_out, int out_size, void* d_ws, size_t ws_size,
                              hipStream_t stream) {
    const float*    x     = (const float*)d_in[0];
    const unsigned* pk    = (const unsigned*)d_in[1];
    const float*    table = (const float*)d_in[2];
    float*          out   = (float*)d_out;

    pe_peak_kernel<<<dim3(S * NBT), dim3(THREADS), 0, stream>>>(x, pk, table, out);
}